// Round 4
// baseline (146.759 us; speedup 1.0000x reference)
//
#include <hip/hip_runtime.h>
#include <math.h>

#define NN 50001
#define DD 128
#define NE 800000

typedef __attribute__((ext_vector_type(8))) short short8;
typedef __attribute__((ext_vector_type(4))) float floatx4;

__device__ __forceinline__ unsigned short f2bf(float f) {
    unsigned u = __builtin_bit_cast(unsigned, f);
    u += 0x7fffu + ((u >> 16) & 1u);          // round-to-nearest-even
    return (unsigned short)(u >> 16);
}
__device__ __forceinline__ float bflo(unsigned u) {   // low 16 bits as bf16 -> f32
    return __builtin_bit_cast(float, u << 16);
}
__device__ __forceinline__ float bfhi(unsigned u) {   // high 16 bits as bf16 -> f32
    return __builtin_bit_cast(float, u & 0xffff0000u);
}
__device__ __forceinline__ float score(float att) {   // leaky-relu(0.2) then exp(x-1)
    att = att >= 0.f ? att : 0.2f * att;
    return __expf(att - 1.f);
}

// K0: blocks 0..63: W_scale (128x128 f32,[k][j]) -> WT bf16 [j][k].
//     blocks 64.. : row_ptr[n] = first edge e with src[e] >= n (src sorted).
__global__ void k_prep(const float* __restrict__ W, unsigned short* __restrict__ WT,
                       const int* __restrict__ edge, int* __restrict__ row_ptr) {
    int b = blockIdx.x;
    if (b < 64) {
        int idx = b * 256 + threadIdx.x;
        int k = idx >> 7, j = idx & 127;
        WT[j * DD + k] = f2bf(W[idx]);
    } else {
        int e = (b - 64) * 256 + threadIdx.x;
        if (e >= NE) return;
        int s = edge[2 * e];
        if (e == 0) {
            for (int n = 0; n <= s; n++) row_ptr[n] = 0;
        } else {
            int p = edge[2 * (e - 1)];
            for (int n = p + 1; n <= s; n++) row_ptr[n] = e;
        }
        if (e == NE - 1) {
            for (int n = s + 1; n <= NN; n++) row_ptr[n] = NE;
        }
    }
}

// K1: item = emb @ W_scale + b_scale (bf16 out), fused a_src/a_dst = item . W_att halves.
// One wave per 16-node tile.
__global__ void __launch_bounds__(256) k_gemm(const float* __restrict__ emb,
        const unsigned short* __restrict__ WT, const float* __restrict__ b_scale,
        const float* __restrict__ W_att, unsigned short* __restrict__ item,
        float* __restrict__ a_src, float* __restrict__ a_dst) {
    int wave = blockIdx.x * 4 + (threadIdx.x >> 6);
    int lane = threadIdx.x & 63;
    int base = wave * 16;
    if (base >= NN) return;
    int m = lane & 15, q = lane >> 4;

    int row = base + m; if (row >= NN) row = NN - 1;
    const float* ap = emb + (long)row * DD + q * 8;
    short8 a[4];
    #pragma unroll
    for (int ks = 0; ks < 4; ks++) {
        float4 f0 = *(const float4*)(ap + ks * 32);
        float4 f1 = *(const float4*)(ap + ks * 32 + 4);
        a[ks][0] = (short)f2bf(f0.x); a[ks][1] = (short)f2bf(f0.y);
        a[ks][2] = (short)f2bf(f0.z); a[ks][3] = (short)f2bf(f0.w);
        a[ks][4] = (short)f2bf(f1.x); a[ks][5] = (short)f2bf(f1.y);
        a[ks][6] = (short)f2bf(f1.z); a[ks][7] = (short)f2bf(f1.w);
    }

    float p_src[4] = {0.f, 0.f, 0.f, 0.f};
    float p_dst[4] = {0.f, 0.f, 0.f, 0.f};

    #pragma unroll
    for (int ft = 0; ft < 8; ft++) {
        int col = ft * 16 + m;
        floatx4 acc = {0.f, 0.f, 0.f, 0.f};
        #pragma unroll
        for (int ks = 0; ks < 4; ks++) {
            short8 b = *(const short8*)(WT + col * DD + ks * 32 + q * 8);
            acc = __builtin_amdgcn_mfma_f32_16x16x32_bf16(a[ks], b, acc, 0, 0, 0);
        }
        float bs = b_scale[col];
        float wsrc = W_att[col], wdst = W_att[DD + col];
        #pragma unroll
        for (int r = 0; r < 4; r++) {
            float v = acc[r] + bs;            // C/D: col = lane&15, row = (lane>>4)*4 + reg
            int gr = base + q * 4 + r;
            if (gr < NN) item[(long)gr * DD + col] = f2bf(v);
            p_src[r] += v * wsrc;
            p_dst[r] += v * wdst;
        }
    }
    #pragma unroll
    for (int off = 1; off <= 8; off <<= 1) {
        #pragma unroll
        for (int r = 0; r < 4; r++) {
            p_src[r] += __shfl_xor(p_src[r], off, 64);
            p_dst[r] += __shfl_xor(p_dst[r], off, 64);
        }
    }
    if (m == 0) {
        #pragma unroll
        for (int r = 0; r < 4; r++) {
            int gr = base + q * 4 + r;
            if (gr < NN) { a_src[gr] = p_src[r]; a_dst[gr] = p_dst[r]; }
        }
    }
}

// K2: fused score + aggregate. One wave per node; lane = 16*g + t.
// Group g owns edges j = g, g+4, g+8, ...; scoring is computed redundantly per group
// (hidden under gather latency). Main loop runs 4 edges per group -> 12 loads in flight.
__global__ void __launch_bounds__(256) k_agg(const int* __restrict__ edge,
        const int* __restrict__ row_ptr, const unsigned short* __restrict__ item,
        const float* __restrict__ a_src, const float* __restrict__ a_dst,
        const float* __restrict__ b_att, float* __restrict__ out) {
    int n = blockIdx.x * 4 + (threadIdx.x >> 6);
    int lane = threadIdx.x & 63;
    if (n >= NN) return;
    int g = lane >> 4, t = lane & 15;

    int start = row_ptr[n];
    int len = row_ptr[n + 1] - start;
    const int* dp = edge + 2 * start + 1;     // dst stream, stride-2 ints

    if (len > 0) {
        float asrc = a_src[n] + b_att[0];
        float acc[8] = {0.f, 0.f, 0.f, 0.f, 0.f, 0.f, 0.f, 0.f};
        float ssum = 0.f;
        int j = g;
        // 4-deep pipelined main loop: 16 edges per wave iteration
        for (; j + 12 < len; j += 16) {
            int d0 = dp[2 * j], d1 = dp[2 * (j + 4)], d2 = dp[2 * (j + 8)], d3 = dp[2 * (j + 12)];
            float x0 = a_dst[d0], x1 = a_dst[d1], x2 = a_dst[d2], x3 = a_dst[d3];
            uint4 u0 = *(const uint4*)(item + (long)d0 * DD + t * 8);
            uint4 u1 = *(const uint4*)(item + (long)d1 * DD + t * 8);
            uint4 u2 = *(const uint4*)(item + (long)d2 * DD + t * 8);
            uint4 u3 = *(const uint4*)(item + (long)d3 * DD + t * 8);
            float s0 = score(asrc + x0), s1 = score(asrc + x1);
            float s2 = score(asrc + x2), s3 = score(asrc + x3);
            ssum += (s0 + s1) + (s2 + s3);
            acc[0] += s0 * bflo(u0.x); acc[1] += s0 * bfhi(u0.x);
            acc[2] += s0 * bflo(u0.y); acc[3] += s0 * bfhi(u0.y);
            acc[4] += s0 * bflo(u0.z); acc[5] += s0 * bfhi(u0.z);
            acc[6] += s0 * bflo(u0.w); acc[7] += s0 * bfhi(u0.w);
            acc[0] += s1 * bflo(u1.x); acc[1] += s1 * bfhi(u1.x);
            acc[2] += s1 * bflo(u1.y); acc[3] += s1 * bfhi(u1.y);
            acc[4] += s1 * bflo(u1.z); acc[5] += s1 * bfhi(u1.z);
            acc[6] += s1 * bflo(u1.w); acc[7] += s1 * bfhi(u1.w);
            acc[0] += s2 * bflo(u2.x); acc[1] += s2 * bfhi(u2.x);
            acc[2] += s2 * bflo(u2.y); acc[3] += s2 * bfhi(u2.y);
            acc[4] += s2 * bflo(u2.z); acc[5] += s2 * bfhi(u2.z);
            acc[6] += s2 * bflo(u2.w); acc[7] += s2 * bfhi(u2.w);
            acc[0] += s3 * bflo(u3.x); acc[1] += s3 * bfhi(u3.x);
            acc[2] += s3 * bflo(u3.y); acc[3] += s3 * bfhi(u3.y);
            acc[4] += s3 * bflo(u3.z); acc[5] += s3 * bfhi(u3.z);
            acc[6] += s3 * bflo(u3.w); acc[7] += s3 * bfhi(u3.w);
        }
        // tail: 1 edge per group per iteration
        for (; j < len; j += 4) {
            int d = dp[2 * j];
            float x = a_dst[d];
            uint4 u = *(const uint4*)(item + (long)d * DD + t * 8);
            float s = score(asrc + x);
            ssum += s;
            acc[0] += s * bflo(u.x); acc[1] += s * bfhi(u.x);
            acc[2] += s * bflo(u.y); acc[3] += s * bfhi(u.y);
            acc[4] += s * bflo(u.z); acc[5] += s * bfhi(u.z);
            acc[6] += s * bflo(u.w); acc[7] += s * bfhi(u.w);
        }
        // combine the 4 edge-groups (lane bits 4,5)
        #pragma unroll
        for (int off = 16; off <= 32; off <<= 1) {
            #pragma unroll
            for (int k = 0; k < 8; k++) acc[k] += __shfl_xor(acc[k], off, 64);
            ssum += __shfl_xor(ssum, off, 64);
        }
        float inv = 1.f / ssum;
        float4 o;
        if (g == 0) {
            o.x = 1.f / (1.f + __expf(-acc[0] * inv));
            o.y = 1.f / (1.f + __expf(-acc[1] * inv));
            o.z = 1.f / (1.f + __expf(-acc[2] * inv));
            o.w = 1.f / (1.f + __expf(-acc[3] * inv));
            *(float4*)(out + (long)n * DD + t * 8) = o;
        } else if (g == 1) {
            o.x = 1.f / (1.f + __expf(-acc[4] * inv));
            o.y = 1.f / (1.f + __expf(-acc[5] * inv));
            o.z = 1.f / (1.f + __expf(-acc[6] * inv));
            o.w = 1.f / (1.f + __expf(-acc[7] * inv));
            *(float4*)(out + (long)n * DD + t * 8 + 4) = o;
        }
    } else {
        float4 h = make_float4(0.5f, 0.5f, 0.5f, 0.5f);   // sigmoid(0)
        if (g == 0)      *(float4*)(out + (long)n * DD + t * 8) = h;
        else if (g == 1) *(float4*)(out + (long)n * DD + t * 8 + 4) = h;
    }
}

extern "C" void kernel_launch(void* const* d_in, const int* in_sizes, int n_in,
                              void* d_out, int out_size, void* d_ws, size_t ws_size,
                              hipStream_t stream) {
    const int*   edge    = (const int*)d_in[0];
    const float* emb     = (const float*)d_in[1];
    const float* W_scale = (const float*)d_in[2];
    const float* b_scale = (const float*)d_in[3];
    const float* W_att   = (const float*)d_in[4];
    const float* b_att   = (const float*)d_in[5];
    float* out = (float*)d_out;

    char* ws = (char*)d_ws;
    unsigned short* WT      = (unsigned short*)(ws);                     // 32768 B
    int*            row_ptr = (int*)(ws + 32768);                        // 200832 B
    float*          a_src   = (float*)(ws + 233600);                     // 200192 B
    float*          a_dst   = (float*)(ws + 433792);                     // 200192 B
    unsigned short* item    = (unsigned short*)(ws + 633984);            // 12800256 B

    int node_blocks = (NN + 3) / 4;          // wave per node, 4 waves/block
    int tile_blocks = ((NN + 15) / 16 + 3) / 4;
    int edge_blocks = (NE + 255) / 256;

    k_prep <<<64 + edge_blocks, 256, 0, stream>>>(W_scale, WT, edge, row_ptr);
    k_gemm <<<tile_blocks,      256, 0, stream>>>(emb, WT, b_scale, W_att, item, a_src, a_dst);
    k_agg  <<<node_blocks,      256, 0, stream>>>(edge, row_ptr, item, a_src, a_dst, b_att, out);
}

// Round 5
// 145.075 us; speedup vs baseline: 1.0116x; 1.0116x over previous
//
#include <hip/hip_runtime.h>
#include <math.h>

#define NN 50001
#define DD 128
#define NE 800000
#define GEMM_BLOCKS 782              // ceil(ceil(50001/16)/4)
#define EDGE_BLOCKS 3125             // ceil(800000/256)

typedef __attribute__((ext_vector_type(8))) short short8;
typedef __attribute__((ext_vector_type(4))) float floatx4;

__device__ __forceinline__ unsigned short f2bf(float f) {
    unsigned u = __builtin_bit_cast(unsigned, f);
    u += 0x7fffu + ((u >> 16) & 1u);          // round-to-nearest-even
    return (unsigned short)(u >> 16);
}
__device__ __forceinline__ float bflo(unsigned u) {   // low 16 bits as bf16 -> f32
    return __builtin_bit_cast(float, u << 16);
}
__device__ __forceinline__ float bfhi(unsigned u) {   // high 16 bits as bf16 -> f32
    return __builtin_bit_cast(float, u & 0xffff0000u);
}
__device__ __forceinline__ float score(float att) {   // leaky-relu(0.2) then exp(x-1)
    att = att >= 0.f ? att : 0.2f * att;
    return __expf(att - 1.f);
}

// K0: W_scale (128x128 f32,[k][j]) -> WT bf16 [j][k]. Tiny (64 blocks).
__global__ void k_prep(const float* __restrict__ W, unsigned short* __restrict__ WT) {
    int idx = blockIdx.x * 256 + threadIdx.x;
    int k = idx >> 7, j = idx & 127;
    WT[j * DD + k] = f2bf(W[idx]);
}

// K1: blocks < GEMM_BLOCKS: item = emb @ W_scale + b_scale (bf16), fused a_src/a_dst.
//     Transposed MFMA operands: A=WT row (feature), B=emb row (node) so the C/D
//     mapping gives node=lane&15, feature=(lane>>4)*4+reg -> each lane packs 4
//     consecutive bf16 features into one 8 B store (8 stores/wave vs 64).
//     blocks >= GEMM_BLOCKS: row_ptr[n] = first edge with src >= n (overlaps GEMM).
__global__ void __launch_bounds__(256) k_gemm(const float* __restrict__ emb,
        const unsigned short* __restrict__ WT, const float* __restrict__ b_scale,
        const float* __restrict__ W_att, const int* __restrict__ edge,
        unsigned short* __restrict__ item, float* __restrict__ a_src,
        float* __restrict__ a_dst, int* __restrict__ row_ptr) {
    if (blockIdx.x >= GEMM_BLOCKS) {                    // ---- rowptr part ----
        int e = (blockIdx.x - GEMM_BLOCKS) * 256 + threadIdx.x;
        if (e >= NE) return;
        int s = edge[2 * e];
        if (e == 0) {
            for (int n = 0; n <= s; n++) row_ptr[n] = 0;
        } else {
            int p = edge[2 * (e - 1)];
            for (int n = p + 1; n <= s; n++) row_ptr[n] = e;
        }
        if (e == NE - 1) {
            for (int n = s + 1; n <= NN; n++) row_ptr[n] = NE;
        }
        return;
    }
    // ---- GEMM part: one wave per 16 nodes ----
    int wave = blockIdx.x * 4 + (threadIdx.x >> 6);
    int lane = threadIdx.x & 63;
    int base = wave * 16;
    if (base >= NN) return;
    int m = lane & 15, q = lane >> 4;
    int node = base + m;
    bool valid = node < NN;

    int row = valid ? node : NN - 1;
    const float* bp = emb + (long)row * DD + q * 8;
    short8 b[4];                                        // B-frag: emb row (node index)
    #pragma unroll
    for (int ks = 0; ks < 4; ks++) {
        float4 f0 = *(const float4*)(bp + ks * 32);
        float4 f1 = *(const float4*)(bp + ks * 32 + 4);
        b[ks][0] = (short)f2bf(f0.x); b[ks][1] = (short)f2bf(f0.y);
        b[ks][2] = (short)f2bf(f0.z); b[ks][3] = (short)f2bf(f0.w);
        b[ks][4] = (short)f2bf(f1.x); b[ks][5] = (short)f2bf(f1.y);
        b[ks][6] = (short)f2bf(f1.z); b[ks][7] = (short)f2bf(f1.w);
    }

    float p_src = 0.f, p_dst = 0.f;

    #pragma unroll
    for (int ft = 0; ft < 8; ft++) {
        floatx4 acc = {0.f, 0.f, 0.f, 0.f};
        const unsigned short* wrow = WT + (ft * 16 + m) * DD;   // A-frag: WT row (feature)
        #pragma unroll
        for (int ks = 0; ks < 4; ks++) {
            short8 a = *(const short8*)(wrow + ks * 32 + q * 8);
            acc = __builtin_amdgcn_mfma_f32_16x16x32_bf16(a, b[ks], acc, 0, 0, 0);
        }
        int fo = ft * 16 + q * 4;
        float4 bs = *(const float4*)(b_scale + fo);
        float4 ws = *(const float4*)(W_att + fo);
        float4 wd = *(const float4*)(W_att + DD + fo);
        float v0 = acc[0] + bs.x, v1 = acc[1] + bs.y;
        float v2 = acc[2] + bs.z, v3 = acc[3] + bs.w;
        if (valid) {
            uint2 pk;
            pk.x = (unsigned)f2bf(v0) | ((unsigned)f2bf(v1) << 16);
            pk.y = (unsigned)f2bf(v2) | ((unsigned)f2bf(v3) << 16);
            *(uint2*)(item + (long)node * DD + fo) = pk;
        }
        p_src += v0 * ws.x + v1 * ws.y + v2 * ws.z + v3 * ws.w;
        p_dst += v0 * wd.x + v1 * wd.y + v2 * wd.z + v3 * wd.w;
    }
    // reduce over q (lane bits 4,5); node is fixed within the reduction
    p_src += __shfl_xor(p_src, 16, 64); p_src += __shfl_xor(p_src, 32, 64);
    p_dst += __shfl_xor(p_dst, 16, 64); p_dst += __shfl_xor(p_dst, 32, 64);
    if (q == 0 && valid) { a_src[node] = p_src; a_dst[node] = p_dst; }
}

// K2: fused score + aggregate. One wave per node; lane = 16*g + t.
// Group g owns edges j = g, g+4, ...; 4-deep pipelined main loop (12 loads in flight).
__global__ void __launch_bounds__(256) k_agg(const int* __restrict__ edge,
        const int* __restrict__ row_ptr, const unsigned short* __restrict__ item,
        const float* __restrict__ a_src, const float* __restrict__ a_dst,
        const float* __restrict__ b_att, float* __restrict__ out) {
    int n = blockIdx.x * 4 + (threadIdx.x >> 6);
    int lane = threadIdx.x & 63;
    if (n >= NN) return;
    int g = lane >> 4, t = lane & 15;

    int start = row_ptr[n];
    int len = row_ptr[n + 1] - start;
    const int* dp = edge + 2 * start + 1;     // dst stream, stride-2 ints

    if (len > 0) {
        float asrc = a_src[n] + b_att[0];
        float acc[8] = {0.f, 0.f, 0.f, 0.f, 0.f, 0.f, 0.f, 0.f};
        float ssum = 0.f;
        int j = g;
        for (; j + 12 < len; j += 16) {
            int d0 = dp[2 * j], d1 = dp[2 * (j + 4)], d2 = dp[2 * (j + 8)], d3 = dp[2 * (j + 12)];
            float x0 = a_dst[d0], x1 = a_dst[d1], x2 = a_dst[d2], x3 = a_dst[d3];
            uint4 u0 = *(const uint4*)(item + (long)d0 * DD + t * 8);
            uint4 u1 = *(const uint4*)(item + (long)d1 * DD + t * 8);
            uint4 u2 = *(const uint4*)(item + (long)d2 * DD + t * 8);
            uint4 u3 = *(const uint4*)(item + (long)d3 * DD + t * 8);
            float s0 = score(asrc + x0), s1 = score(asrc + x1);
            float s2 = score(asrc + x2), s3 = score(asrc + x3);
            ssum += (s0 + s1) + (s2 + s3);
            acc[0] += s0 * bflo(u0.x); acc[1] += s0 * bfhi(u0.x);
            acc[2] += s0 * bflo(u0.y); acc[3] += s0 * bfhi(u0.y);
            acc[4] += s0 * bflo(u0.z); acc[5] += s0 * bfhi(u0.z);
            acc[6] += s0 * bflo(u0.w); acc[7] += s0 * bfhi(u0.w);
            acc[0] += s1 * bflo(u1.x); acc[1] += s1 * bfhi(u1.x);
            acc[2] += s1 * bflo(u1.y); acc[3] += s1 * bfhi(u1.y);
            acc[4] += s1 * bflo(u1.z); acc[5] += s1 * bfhi(u1.z);
            acc[6] += s1 * bflo(u1.w); acc[7] += s1 * bfhi(u1.w);
            acc[0] += s2 * bflo(u2.x); acc[1] += s2 * bfhi(u2.x);
            acc[2] += s2 * bflo(u2.y); acc[3] += s2 * bfhi(u2.y);
            acc[4] += s2 * bflo(u2.z); acc[5] += s2 * bfhi(u2.z);
            acc[6] += s2 * bflo(u2.w); acc[7] += s2 * bfhi(u2.w);
            acc[0] += s3 * bflo(u3.x); acc[1] += s3 * bfhi(u3.x);
            acc[2] += s3 * bflo(u3.y); acc[3] += s3 * bfhi(u3.y);
            acc[4] += s3 * bflo(u3.z); acc[5] += s3 * bfhi(u3.z);
            acc[6] += s3 * bflo(u3.w); acc[7] += s3 * bfhi(u3.w);
        }
        for (; j < len; j += 4) {
            int d = dp[2 * j];
            float x = a_dst[d];
            uint4 u = *(const uint4*)(item + (long)d * DD + t * 8);
            float s = score(asrc + x);
            ssum += s;
            acc[0] += s * bflo(u.x); acc[1] += s * bfhi(u.x);
            acc[2] += s * bflo(u.y); acc[3] += s * bfhi(u.y);
            acc[4] += s * bflo(u.z); acc[5] += s * bfhi(u.z);
            acc[6] += s * bflo(u.w); acc[7] += s * bfhi(u.w);
        }
        #pragma unroll
        for (int off = 16; off <= 32; off <<= 1) {
            #pragma unroll
            for (int k = 0; k < 8; k++) acc[k] += __shfl_xor(acc[k], off, 64);
            ssum += __shfl_xor(ssum, off, 64);
        }
        float inv = 1.f / ssum;
        float4 o;
        if (g == 0) {
            o.x = 1.f / (1.f + __expf(-acc[0] * inv));
            o.y = 1.f / (1.f + __expf(-acc[1] * inv));
            o.z = 1.f / (1.f + __expf(-acc[2] * inv));
            o.w = 1.f / (1.f + __expf(-acc[3] * inv));
            *(float4*)(out + (long)n * DD + t * 8) = o;
        } else if (g == 1) {
            o.x = 1.f / (1.f + __expf(-acc[4] * inv));
            o.y = 1.f / (1.f + __expf(-acc[5] * inv));
            o.z = 1.f / (1.f + __expf(-acc[6] * inv));
            o.w = 1.f / (1.f + __expf(-acc[7] * inv));
            *(float4*)(out + (long)n * DD + t * 8 + 4) = o;
        }
    } else {
        float4 h = make_float4(0.5f, 0.5f, 0.5f, 0.5f);   // sigmoid(0)
        if (g == 0)      *(float4*)(out + (long)n * DD + t * 8) = h;
        else if (g == 1) *(float4*)(out + (long)n * DD + t * 8 + 4) = h;
    }
}

extern "C" void kernel_launch(void* const* d_in, const int* in_sizes, int n_in,
                              void* d_out, int out_size, void* d_ws, size_t ws_size,
                              hipStream_t stream) {
    const int*   edge    = (const int*)d_in[0];
    const float* emb     = (const float*)d_in[1];
    const float* W_scale = (const float*)d_in[2];
    const float* b_scale = (const float*)d_in[3];
    const float* W_att   = (const float*)d_in[4];
    const float* b_att   = (const float*)d_in[5];
    float* out = (float*)d_out;

    char* ws = (char*)d_ws;
    unsigned short* WT      = (unsigned short*)(ws);                     // 32768 B
    int*            row_ptr = (int*)(ws + 32768);                        // 200832 B
    float*          a_src   = (float*)(ws + 233600);                     // 200192 B
    float*          a_dst   = (float*)(ws + 433792);                     // 200192 B
    unsigned short* item    = (unsigned short*)(ws + 633984);            // 12800256 B

    int node_blocks = (NN + 3) / 4;          // wave per node, 4 waves/block

    k_prep <<<64,                        256, 0, stream>>>(W_scale, WT);
    k_gemm <<<GEMM_BLOCKS + EDGE_BLOCKS, 256, 0, stream>>>(emb, WT, b_scale, W_att,
                                                           edge, item, a_src, a_dst, row_ptr);
    k_agg  <<<node_blocks,               256, 0, stream>>>(edge, row_ptr, item,
                                                           a_src, a_dst, b_att, out);
}

// Round 6
// 142.443 us; speedup vs baseline: 1.0303x; 1.0185x over previous
//
#include <hip/hip_runtime.h>
#include <math.h>

#define NN 50001
#define DD 128
#define NE 800000
#define GEMM_BLOCKS 782              // ceil(ceil(50001/16)/4)
#define EDGE_BLOCKS 3125             // ceil(800000/256)
#define WSTRIDE 132                  // LDS row stride in shorts (128+4 pad)

typedef __attribute__((ext_vector_type(8))) short short8;
typedef __attribute__((ext_vector_type(4))) float floatx4;

__device__ __forceinline__ unsigned short f2bf(float f) {
    unsigned u = __builtin_bit_cast(unsigned, f);
    u += 0x7fffu + ((u >> 16) & 1u);          // round-to-nearest-even
    return (unsigned short)(u >> 16);
}
__device__ __forceinline__ float bflo(unsigned u) {   // low 16 bits as bf16 -> f32
    return __builtin_bit_cast(float, u << 16);
}
__device__ __forceinline__ float bfhi(unsigned u) {   // high 16 bits as bf16 -> f32
    return __builtin_bit_cast(float, u & 0xffff0000u);
}
__device__ __forceinline__ float score(float att) {   // leaky-relu(0.2) then exp(x-1)
    att = att >= 0.f ? att : 0.2f * att;
    return __expf(att - 1.f);
}

// K1: blocks < GEMM_BLOCKS: item = emb @ W_scale + b_scale (bf16), fused a_src/a_dst.
//     W is converted f32->bf16 transposed into LDS per block (64 KB L2-resident source),
//     killing the separate k_prep dispatch. MFMA operands: A=W^T row (feature),
//     B=emb row (node) -> C/D maps node=lane&15, feature=(lane>>4)*4+reg, so each lane
//     packs 4 consecutive bf16 features into one 8 B store.
//     blocks >= GEMM_BLOCKS: row_ptr[n] = first edge with src >= n (overlaps GEMM).
__global__ void __launch_bounds__(256) k_gemm(const float* __restrict__ emb,
        const float* __restrict__ W, const float* __restrict__ b_scale,
        const float* __restrict__ W_att, const int* __restrict__ edge,
        unsigned short* __restrict__ item, float* __restrict__ a_src,
        float* __restrict__ a_dst, int* __restrict__ row_ptr) {
    if (blockIdx.x >= GEMM_BLOCKS) {                    // ---- rowptr part ----
        int e = (blockIdx.x - GEMM_BLOCKS) * 256 + threadIdx.x;
        if (e >= NE) return;
        int s = edge[2 * e];
        if (e == 0) {
            for (int n = 0; n <= s; n++) row_ptr[n] = 0;
        } else {
            int p = edge[2 * (e - 1)];
            for (int n = p + 1; n <= s; n++) row_ptr[n] = e;
        }
        if (e == NE - 1) {
            for (int n = s + 1; n <= NN; n++) row_ptr[n] = NE;
        }
        return;
    }
    // ---- GEMM part: one wave per 16 nodes ----
    __shared__ unsigned short WTl[DD * WSTRIDE];        // 33792 B, [feature][k]
    {
        const float4* Wv = (const float4*)W;            // 4096 float4s, coalesced
        #pragma unroll
        for (int it = 0; it < 16; it++) {
            int f = it * 256 + threadIdx.x;
            int k = f >> 5;                             // W row (contraction index)
            int j4 = (f & 31) * 4;                      // feature columns j4..j4+3
            float4 w = Wv[f];
            WTl[(j4 + 0) * WSTRIDE + k] = f2bf(w.x);
            WTl[(j4 + 1) * WSTRIDE + k] = f2bf(w.y);
            WTl[(j4 + 2) * WSTRIDE + k] = f2bf(w.z);
            WTl[(j4 + 3) * WSTRIDE + k] = f2bf(w.w);
        }
    }
    __syncthreads();

    int wave = blockIdx.x * 4 + (threadIdx.x >> 6);
    int lane = threadIdx.x & 63;
    int base = wave * 16;
    if (base >= NN) return;
    int m = lane & 15, q = lane >> 4;
    int node = base + m;
    bool valid = node < NN;

    int row = valid ? node : NN - 1;
    const float* bp = emb + (long)row * DD + q * 8;
    short8 b[4];                                        // B-frag: emb row (node index)
    #pragma unroll
    for (int ks = 0; ks < 4; ks++) {
        float4 f0 = *(const float4*)(bp + ks * 32);
        float4 f1 = *(const float4*)(bp + ks * 32 + 4);
        b[ks][0] = (short)f2bf(f0.x); b[ks][1] = (short)f2bf(f0.y);
        b[ks][2] = (short)f2bf(f0.z); b[ks][3] = (short)f2bf(f0.w);
        b[ks][4] = (short)f2bf(f1.x); b[ks][5] = (short)f2bf(f1.y);
        b[ks][6] = (short)f2bf(f1.z); b[ks][7] = (short)f2bf(f1.w);
    }

    float p_src = 0.f, p_dst = 0.f;

    #pragma unroll
    for (int ft = 0; ft < 8; ft++) {
        floatx4 acc = {0.f, 0.f, 0.f, 0.f};
        const unsigned short* wrow = WTl + (ft * 16 + m) * WSTRIDE;  // A-frag: feature row
        #pragma unroll
        for (int ks = 0; ks < 4; ks++) {
            short8 a = *(const short8*)(wrow + ks * 32 + q * 8);     // ds_read_b128
            acc = __builtin_amdgcn_mfma_f32_16x16x32_bf16(a, b[ks], acc, 0, 0, 0);
        }
        int fo = ft * 16 + q * 4;
        float4 bs = *(const float4*)(b_scale + fo);
        float4 ws = *(const float4*)(W_att + fo);
        float4 wd = *(const float4*)(W_att + DD + fo);
        float v0 = acc[0] + bs.x, v1 = acc[1] + bs.y;
        float v2 = acc[2] + bs.z, v3 = acc[3] + bs.w;
        if (valid) {
            uint2 pk;
            pk.x = (unsigned)f2bf(v0) | ((unsigned)f2bf(v1) << 16);
            pk.y = (unsigned)f2bf(v2) | ((unsigned)f2bf(v3) << 16);
            *(uint2*)(item + (long)node * DD + fo) = pk;
        }
        p_src += v0 * ws.x + v1 * ws.y + v2 * ws.z + v3 * ws.w;
        p_dst += v0 * wd.x + v1 * wd.y + v2 * wd.z + v3 * wd.w;
    }
    // reduce over q (lane bits 4,5); node is fixed within the reduction
    p_src += __shfl_xor(p_src, 16, 64); p_src += __shfl_xor(p_src, 32, 64);
    p_dst += __shfl_xor(p_dst, 16, 64); p_dst += __shfl_xor(p_dst, 32, 64);
    if (q == 0 && valid) { a_src[node] = p_src; a_dst[node] = p_dst; }
}

// K2: fused score + aggregate. One wave per node; lane = 16*g + t.
// Group g owns edges j = g, g+4, ...; 4-deep pipelined main loop (12 loads in flight).
__global__ void __launch_bounds__(256) k_agg(const int* __restrict__ edge,
        const int* __restrict__ row_ptr, const unsigned short* __restrict__ item,
        const float* __restrict__ a_src, const float* __restrict__ a_dst,
        const float* __restrict__ b_att, float* __restrict__ out) {
    int n = blockIdx.x * 4 + (threadIdx.x >> 6);
    int lane = threadIdx.x & 63;
    if (n >= NN) return;
    int g = lane >> 4, t = lane & 15;

    int start = row_ptr[n];
    int len = row_ptr[n + 1] - start;
    const int* dp = edge + 2 * start + 1;     // dst stream, stride-2 ints

    if (len > 0) {
        float asrc = a_src[n] + b_att[0];
        float acc[8] = {0.f, 0.f, 0.f, 0.f, 0.f, 0.f, 0.f, 0.f};
        float ssum = 0.f;
        int j = g;
        for (; j + 12 < len; j += 16) {
            int d0 = dp[2 * j], d1 = dp[2 * (j + 4)], d2 = dp[2 * (j + 8)], d3 = dp[2 * (j + 12)];
            float x0 = a_dst[d0], x1 = a_dst[d1], x2 = a_dst[d2], x3 = a_dst[d3];
            uint4 u0 = *(const uint4*)(item + (long)d0 * DD + t * 8);
            uint4 u1 = *(const uint4*)(item + (long)d1 * DD + t * 8);
            uint4 u2 = *(const uint4*)(item + (long)d2 * DD + t * 8);
            uint4 u3 = *(const uint4*)(item + (long)d3 * DD + t * 8);
            float s0 = score(asrc + x0), s1 = score(asrc + x1);
            float s2 = score(asrc + x2), s3 = score(asrc + x3);
            ssum += (s0 + s1) + (s2 + s3);
            acc[0] += s0 * bflo(u0.x); acc[1] += s0 * bfhi(u0.x);
            acc[2] += s0 * bflo(u0.y); acc[3] += s0 * bfhi(u0.y);
            acc[4] += s0 * bflo(u0.z); acc[5] += s0 * bfhi(u0.z);
            acc[6] += s0 * bflo(u0.w); acc[7] += s0 * bfhi(u0.w);
            acc[0] += s1 * bflo(u1.x); acc[1] += s1 * bfhi(u1.x);
            acc[2] += s1 * bflo(u1.y); acc[3] += s1 * bfhi(u1.y);
            acc[4] += s1 * bflo(u1.z); acc[5] += s1 * bfhi(u1.z);
            acc[6] += s1 * bflo(u1.w); acc[7] += s1 * bfhi(u1.w);
            acc[0] += s2 * bflo(u2.x); acc[1] += s2 * bfhi(u2.x);
            acc[2] += s2 * bflo(u2.y); acc[3] += s2 * bfhi(u2.y);
            acc[4] += s2 * bflo(u2.z); acc[5] += s2 * bfhi(u2.z);
            acc[6] += s2 * bflo(u2.w); acc[7] += s2 * bfhi(u2.w);
            acc[0] += s3 * bflo(u3.x); acc[1] += s3 * bfhi(u3.x);
            acc[2] += s3 * bflo(u3.y); acc[3] += s3 * bfhi(u3.y);
            acc[4] += s3 * bflo(u3.z); acc[5] += s3 * bfhi(u3.z);
            acc[6] += s3 * bflo(u3.w); acc[7] += s3 * bfhi(u3.w);
        }
        for (; j < len; j += 4) {
            int d = dp[2 * j];
            float x = a_dst[d];
            uint4 u = *(const uint4*)(item + (long)d * DD + t * 8);
            float s = score(asrc + x);
            ssum += s;
            acc[0] += s * bflo(u.x); acc[1] += s * bfhi(u.x);
            acc[2] += s * bflo(u.y); acc[3] += s * bfhi(u.y);
            acc[4] += s * bflo(u.z); acc[5] += s * bfhi(u.z);
            acc[6] += s * bflo(u.w); acc[7] += s * bfhi(u.w);
        }
        #pragma unroll
        for (int off = 16; off <= 32; off <<= 1) {
            #pragma unroll
            for (int k = 0; k < 8; k++) acc[k] += __shfl_xor(acc[k], off, 64);
            ssum += __shfl_xor(ssum, off, 64);
        }
        float inv = 1.f / ssum;
        float4 o;
        if (g == 0) {
            o.x = 1.f / (1.f + __expf(-acc[0] * inv));
            o.y = 1.f / (1.f + __expf(-acc[1] * inv));
            o.z = 1.f / (1.f + __expf(-acc[2] * inv));
            o.w = 1.f / (1.f + __expf(-acc[3] * inv));
            *(float4*)(out + (long)n * DD + t * 8) = o;
        } else if (g == 1) {
            o.x = 1.f / (1.f + __expf(-acc[4] * inv));
            o.y = 1.f / (1.f + __expf(-acc[5] * inv));
            o.z = 1.f / (1.f + __expf(-acc[6] * inv));
            o.w = 1.f / (1.f + __expf(-acc[7] * inv));
            *(float4*)(out + (long)n * DD + t * 8 + 4) = o;
        }
    } else {
        float4 h = make_float4(0.5f, 0.5f, 0.5f, 0.5f);   // sigmoid(0)
        if (g == 0)      *(float4*)(out + (long)n * DD + t * 8) = h;
        else if (g == 1) *(float4*)(out + (long)n * DD + t * 8 + 4) = h;
    }
}

extern "C" void kernel_launch(void* const* d_in, const int* in_sizes, int n_in,
                              void* d_out, int out_size, void* d_ws, size_t ws_size,
                              hipStream_t stream) {
    const int*   edge    = (const int*)d_in[0];
    const float* emb     = (const float*)d_in[1];
    const float* W_scale = (const float*)d_in[2];
    const float* b_scale = (const float*)d_in[3];
    const float* W_att   = (const float*)d_in[4];
    const float* b_att   = (const float*)d_in[5];
    float* out = (float*)d_out;

    char* ws = (char*)d_ws;
    int*            row_ptr = (int*)(ws);                                // 200832 B
    float*          a_src   = (float*)(ws + 200832);                     // 200192 B
    float*          a_dst   = (float*)(ws + 401024);                     // 200192 B
    unsigned short* item    = (unsigned short*)(ws + 601216);            // 12800256 B

    int node_blocks = (NN + 3) / 4;          // wave per node, 4 waves/block

    k_gemm <<<GEMM_BLOCKS + EDGE_BLOCKS, 256, 0, stream>>>(emb, W_scale, b_scale, W_att,
                                                           edge, item, a_src, a_dst, row_ptr);
    k_agg  <<<node_blocks,               256, 0, stream>>>(edge, row_ptr, item,
                                                           a_src, a_dst, b_att, out);
}

// Round 8
// 141.482 us; speedup vs baseline: 1.0373x; 1.0068x over previous
//
#include <hip/hip_runtime.h>
#include <math.h>

#define NN 50001
#define DD 128
#define NE 800000
#define GEMM_BLOCKS 782              // ceil(ceil(50001/16)/4)
#define EDGE_BLOCKS 3125             // ceil(800000/256)
#define WSTRIDE 132                  // LDS row stride in shorts (128+4 pad)

typedef __attribute__((ext_vector_type(8))) short short8;
typedef __attribute__((ext_vector_type(4))) float floatx4;

__device__ __forceinline__ unsigned short f2bf(float f) {
    unsigned u = __builtin_bit_cast(unsigned, f);
    u += 0x7fffu + ((u >> 16) & 1u);          // round-to-nearest-even
    return (unsigned short)(u >> 16);
}
__device__ __forceinline__ float bflo(unsigned u) {   // low 16 bits as bf16 -> f32
    return __builtin_bit_cast(float, u << 16);
}
__device__ __forceinline__ float bfhi(unsigned u) {   // high 16 bits as bf16 -> f32
    return __builtin_bit_cast(float, u & 0xffff0000u);
}
__device__ __forceinline__ float score(float att) {   // leaky-relu(0.2) then exp(x-1)
    att = att >= 0.f ? att : 0.2f * att;
    return __expf(att - 1.f);
}

// K1: blocks < GEMM_BLOCKS: item = emb @ W_scale + b_scale (bf16), fused a_src/a_dst.
//     W is converted f32->bf16 transposed into LDS per block (64 KB L2-resident source).
//     MFMA operands: A=W^T row (feature), B=emb row (node) -> C/D maps node=lane&15,
//     feature=(lane>>4)*4+reg, so each lane packs 4 consecutive bf16 features into one
//     8 B store. b_att is folded into a_src here.
//     blocks >= GEMM_BLOCKS: row_ptr[n] = first edge with src >= n (overlaps GEMM).
__global__ void __launch_bounds__(256) k_gemm(const float* __restrict__ emb,
        const float* __restrict__ W, const float* __restrict__ b_scale,
        const float* __restrict__ W_att, const int* __restrict__ edge,
        unsigned short* __restrict__ item, float* __restrict__ a_src,
        float* __restrict__ a_dst, int* __restrict__ row_ptr,
        const float* __restrict__ b_att) {
    if (blockIdx.x >= GEMM_BLOCKS) {                    // ---- rowptr part ----
        int e = (blockIdx.x - GEMM_BLOCKS) * 256 + threadIdx.x;
        if (e >= NE) return;
        int s = edge[2 * e];
        if (e == 0) {
            for (int n = 0; n <= s; n++) row_ptr[n] = 0;
        } else {
            int p = edge[2 * (e - 1)];
            for (int n = p + 1; n <= s; n++) row_ptr[n] = e;
        }
        if (e == NE - 1) {
            for (int n = s + 1; n <= NN; n++) row_ptr[n] = NE;
        }
        return;
    }
    // ---- GEMM part: one wave per 16 nodes ----
    __shared__ unsigned short WTl[DD * WSTRIDE];        // 33792 B, [feature][k]
    {
        const float4* Wv = (const float4*)W;            // 4096 float4s, coalesced
        #pragma unroll
        for (int it = 0; it < 16; it++) {
            int f = it * 256 + threadIdx.x;
            int k = f >> 5;                             // contraction index
            int j4 = (f & 31) * 4;                      // feature columns j4..j4+3
            float4 w = Wv[f];
            WTl[(j4 + 0) * WSTRIDE + k] = f2bf(w.x);
            WTl[(j4 + 1) * WSTRIDE + k] = f2bf(w.y);
            WTl[(j4 + 2) * WSTRIDE + k] = f2bf(w.z);
            WTl[(j4 + 3) * WSTRIDE + k] = f2bf(w.w);
        }
    }
    __syncthreads();

    int wave = blockIdx.x * 4 + (threadIdx.x >> 6);
    int lane = threadIdx.x & 63;
    int base = wave * 16;
    if (base >= NN) return;
    int m = lane & 15, q = lane >> 4;
    int node = base + m;
    bool valid = node < NN;

    int row = valid ? node : NN - 1;
    const float* bp = emb + (long)row * DD + q * 8;
    short8 b[4];                                        // B-frag: emb row (node index)
    #pragma unroll
    for (int ks = 0; ks < 4; ks++) {
        float4 f0 = *(const float4*)(bp + ks * 32);
        float4 f1 = *(const float4*)(bp + ks * 32 + 4);
        b[ks][0] = (short)f2bf(f0.x); b[ks][1] = (short)f2bf(f0.y);
        b[ks][2] = (short)f2bf(f0.z); b[ks][3] = (short)f2bf(f0.w);
        b[ks][4] = (short)f2bf(f1.x); b[ks][5] = (short)f2bf(f1.y);
        b[ks][6] = (short)f2bf(f1.z); b[ks][7] = (short)f2bf(f1.w);
    }

    float p_src = 0.f, p_dst = 0.f;

    #pragma unroll
    for (int ft = 0; ft < 8; ft++) {
        floatx4 acc = {0.f, 0.f, 0.f, 0.f};
        const unsigned short* wrow = WTl + (ft * 16 + m) * WSTRIDE;  // A-frag: feature row
        #pragma unroll
        for (int ks = 0; ks < 4; ks++) {
            short8 a = *(const short8*)(wrow + ks * 32 + q * 8);     // ds_read_b128
            acc = __builtin_amdgcn_mfma_f32_16x16x32_bf16(a, b[ks], acc, 0, 0, 0);
        }
        int fo = ft * 16 + q * 4;
        float4 bs = *(const float4*)(b_scale + fo);
        float4 ws = *(const float4*)(W_att + fo);
        float4 wd = *(const float4*)(W_att + DD + fo);
        float v0 = acc[0] + bs.x, v1 = acc[1] + bs.y;
        float v2 = acc[2] + bs.z, v3 = acc[3] + bs.w;
        if (valid) {
            uint2 pk;
            pk.x = (unsigned)f2bf(v0) | ((unsigned)f2bf(v1) << 16);
            pk.y = (unsigned)f2bf(v2) | ((unsigned)f2bf(v3) << 16);
            *(uint2*)(item + (long)node * DD + fo) = pk;
        }
        p_src += v0 * ws.x + v1 * ws.y + v2 * ws.z + v3 * ws.w;
        p_dst += v0 * wd.x + v1 * wd.y + v2 * wd.z + v3 * wd.w;
    }
    // reduce over q (lane bits 4,5); node is fixed within the reduction
    p_src += __shfl_xor(p_src, 16, 64); p_src += __shfl_xor(p_src, 32, 64);
    p_dst += __shfl_xor(p_dst, 16, 64); p_dst += __shfl_xor(p_dst, 32, 64);
    if (q == 0 && valid) { a_src[node] = p_src + b_att[0]; a_dst[node] = p_dst; }
}

// K2: fused score + aggregate. One wave per node; lane = 16*g + t.
// Group g owns edges j = g, g+4, ...; 4-deep pipelined main loop (12 loads in flight).
__global__ void __launch_bounds__(256) k_agg(const int* __restrict__ edge,
        const int* __restrict__ row_ptr, const unsigned short* __restrict__ item,
        const float* __restrict__ a_src, const float* __restrict__ a_dst,
        float* __restrict__ out) {
    int n = blockIdx.x * 4 + (threadIdx.x >> 6);
    int lane = threadIdx.x & 63;
    if (n >= NN) return;
    int g = lane >> 4, t = lane & 15;

    int start = row_ptr[n];
    int len = row_ptr[n + 1] - start;
    const int* dp = edge + 2 * start + 1;     // dst stream, stride-2 ints

    if (len > 0) {
        float asrc = a_src[n];                // b_att already folded in
        float acc[8] = {0.f, 0.f, 0.f, 0.f, 0.f, 0.f, 0.f, 0.f};
        float ssum = 0.f;
        int j = g;
        for (; j + 12 < len; j += 16) {
            int d0 = dp[2 * j], d1 = dp[2 * (j + 4)], d2 = dp[2 * (j + 8)], d3 = dp[2 * (j + 12)];
            float x0 = a_dst[d0], x1 = a_dst[d1], x2 = a_dst[d2], x3 = a_dst[d3];
            uint4 u0 = *(const uint4*)(item + (long)d0 * DD + t * 8);
            uint4 u1 = *(const uint4*)(item + (long)d1 * DD + t * 8);
            uint4 u2 = *(const uint4*)(item + (long)d2 * DD + t * 8);
            uint4 u3 = *(const uint4*)(item + (long)d3 * DD + t * 8);
            float s0 = score(asrc + x0), s1 = score(asrc + x1);
            float s2 = score(asrc + x2), s3 = score(asrc + x3);
            ssum += (s0 + s1) + (s2 + s3);
            acc[0] += s0 * bflo(u0.x); acc[1] += s0 * bfhi(u0.x);
            acc[2] += s0 * bflo(u0.y); acc[3] += s0 * bfhi(u0.y);
            acc[4] += s0 * bflo(u0.z); acc[5] += s0 * bfhi(u0.z);
            acc[6] += s0 * bflo(u0.w); acc[7] += s0 * bfhi(u0.w);
            acc[0] += s1 * bflo(u1.x); acc[1] += s1 * bfhi(u1.x);
            acc[2] += s1 * bflo(u1.y); acc[3] += s1 * bfhi(u1.y);
            acc[4] += s1 * bflo(u1.z); acc[5] += s1 * bfhi(u1.z);
            acc[6] += s1 * bflo(u1.w); acc[7] += s1 * bfhi(u1.w);
            acc[0] += s2 * bflo(u2.x); acc[1] += s2 * bfhi(u2.x);
            acc[2] += s2 * bflo(u2.y); acc[3] += s2 * bfhi(u2.y);
            acc[4] += s2 * bflo(u2.z); acc[5] += s2 * bfhi(u2.z);
            acc[6] += s2 * bflo(u2.w); acc[7] += s2 * bfhi(u2.w);
            acc[0] += s3 * bflo(u3.x); acc[1] += s3 * bfhi(u3.x);
            acc[2] += s3 * bflo(u3.y); acc[3] += s3 * bfhi(u3.y);
            acc[4] += s3 * bflo(u3.z); acc[5] += s3 * bfhi(u3.z);
            acc[6] += s3 * bflo(u3.w); acc[7] += s3 * bfhi(u3.w);
        }
        for (; j < len; j += 4) {
            int d = dp[2 * j];
            float x = a_dst[d];
            uint4 u = *(const uint4*)(item + (long)d * DD + t * 8);
            float s = score(asrc + x);
            ssum += s;
            acc[0] += s * bflo(u.x); acc[1] += s * bfhi(u.x);
            acc[2] += s * bflo(u.y); acc[3] += s * bfhi(u.y);
            acc[4] += s * bflo(u.z); acc[5] += s * bfhi(u.z);
            acc[6] += s * bflo(u.w); acc[7] += s * bfhi(u.w);
        }
        #pragma unroll
        for (int off = 16; off <= 32; off <<= 1) {
            #pragma unroll
            for (int k = 0; k < 8; k++) acc[k] += __shfl_xor(acc[k], off, 64);
            ssum += __shfl_xor(ssum, off, 64);
        }
        float inv = 1.f / ssum;
        float4 o;
        if (g == 0) {
            o.x = 1.f / (1.f + __expf(-acc[0] * inv));
            o.y = 1.f / (1.f + __expf(-acc[1] * inv));
            o.z = 1.f / (1.f + __expf(-acc[2] * inv));
            o.w = 1.f / (1.f + __expf(-acc[3] * inv));
            *(float4*)(out + (long)n * DD + t * 8) = o;
        } else if (g == 1) {
            o.x = 1.f / (1.f + __expf(-acc[4] * inv));
            o.y = 1.f / (1.f + __expf(-acc[5] * inv));
            o.z = 1.f / (1.f + __expf(-acc[6] * inv));
            o.w = 1.f / (1.f + __expf(-acc[7] * inv));
            *(float4*)(out + (long)n * DD + t * 8 + 4) = o;
        }
    } else {
        float4 h = make_float4(0.5f, 0.5f, 0.5f, 0.5f);   // sigmoid(0)
        if (g == 0)      *(float4*)(out + (long)n * DD + t * 8) = h;
        else if (g == 1) *(float4*)(out + (long)n * DD + t * 8 + 4) = h;
    }
}

extern "C" void kernel_launch(void* const* d_in, const int* in_sizes, int n_in,
                              void* d_out, int out_size, void* d_ws, size_t ws_size,
                              hipStream_t stream) {
    const int*   edge    = (const int*)d_in[0];
    const float* emb     = (const float*)d_in[1];
    const float* W_scale = (const float*)d_in[2];
    const float* b_scale = (const float*)d_in[3];
    const float* W_att   = (const float*)d_in[4];
    const float* b_att   = (const float*)d_in[5];
    float* out = (float*)d_out;

    char* ws = (char*)d_ws;
    int*            row_ptr = (int*)(ws);                                // 200832 B
    float*          a_src   = (float*)(ws + 200832);                     // 200192 B
    float*          a_dst   = (float*)(ws + 401024);                     // 200192 B
    unsigned short* item    = (unsigned short*)(ws + 601216);            // 12800256 B

    int node_blocks = (NN + 3) / 4;          // wave per node, 4 waves/block

    k_gemm <<<GEMM_BLOCKS + EDGE_BLOCKS, 256, 0, stream>>>(emb, W_scale, b_scale, W_att,
                                                           edge, item, a_src, a_dst,
                                                           row_ptr, b_att);
    k_agg  <<<node_blocks,               256, 0, stream>>>(edge, row_ptr, item,
                                                           a_src, a_dst, out);
}